// Round 1
// baseline (241.872 us; speedup 1.0000x reference)
//
#include <hip/hip_runtime.h>
#include <math.h>

#define L_SEQ   2048
#define BATCH_N 8
#define H_DIM   1024
#define P_DIM   512
#define M_DIM   (BATCH_N * L_SEQ)   // 16384
#define N2      1024                // packed complex width (re | im)
#define NC      32                  // scan chunks
#define T_CHUNK 64                  // L_SEQ / NC

typedef __attribute__((ext_vector_type(8))) __bf16 bf16x8;
typedef __attribute__((ext_vector_type(4))) float f32x4;

__device__ __forceinline__ unsigned f2bf_bits(float f) {
    unsigned u = __builtin_bit_cast(unsigned, f);
    return (u + 0x7fffu + ((u >> 16) & 1u)) >> 16;   // RNE
}
__device__ __forceinline__ float bf_lo(unsigned v) {
    return __builtin_bit_cast(float, v << 16);
}
__device__ __forceinline__ float bf_hi(unsigned v) {
    return __builtin_bit_cast(float, v & 0xffff0000u);
}
__device__ __forceinline__ float bf2f(unsigned short u) {
    return __builtin_bit_cast(float, (unsigned)u << 16);
}

#define ASYNC_COPY16(gsrc, ldst)                                            \
    __builtin_amdgcn_global_load_lds(                                       \
        (__attribute__((address_space(1))) void*)(gsrc),                    \
        (__attribute__((address_space(3))) void*)(ldst), 16, 0, 0)

// ---------------------------------------------------------------------------
// lam buffer: [lam_re(512) | lam_im(512) | g_re(512) | g_im(512)]  (fp32)
// ---------------------------------------------------------------------------
__global__ void setup_lam(const float* __restrict__ Lre_in,
                          const float* __restrict__ Lim_in,
                          const float* __restrict__ log_step,
                          float* __restrict__ lam) {
    int p = blockIdx.x * blockDim.x + threadIdx.x;
    if (p >= P_DIM) return;
    float step = expf(log_step[p]);
    float c = Lre_in[p];
    float d = Lim_in[p];
    float mag = expf(c * step);
    float ang = d * step;
    float lr = mag * cosf(ang);
    float li = mag * sinf(ang);
    float a = lr - 1.0f, b = li;
    float inv = 1.0f / (c * c + d * d);
    lam[p]             = lr;
    lam[P_DIM + p]     = li;
    lam[2 * P_DIM + p] = (a * c + b * d) * inv;   // g_re
    lam[3 * P_DIM + p] = (b * c - a * d) * inv;   // g_im
}

// Fused weight build.
// W1[n][k] bf16 (N2 x H): n<512 -> B_bar_re, n>=512 -> B_bar_im
// W2[h][k] bf16 (H x N2): k<512 -> 2*C_re,   k>=512 -> -2*C_im
__global__ void build_W(const float* __restrict__ B,
                        const float* __restrict__ C,
                        const float* __restrict__ lam,
                        unsigned short* __restrict__ W1,
                        unsigned short* __restrict__ W2) {
    int idx = blockIdx.x * blockDim.x + threadIdx.x;
    if (idx < P_DIM * H_DIM) {                       // W1 half: idx over P*H
        int p = idx >> 10;
        int h = idx & (H_DIM - 1);
        float bre = B[(size_t)idx * 2];
        float bim = B[(size_t)idx * 2 + 1];
        float gre = lam[2 * P_DIM + p];
        float gim = lam[3 * P_DIM + p];
        W1[(size_t)p * H_DIM + h]           = (unsigned short)f2bf_bits(gre * bre - gim * bim);
        W1[(size_t)(P_DIM + p) * H_DIM + h] = (unsigned short)f2bf_bits(gre * bim + gim * bre);
    } else {                                         // W2 half: idx over H*P
        int j = idx - P_DIM * H_DIM;
        int h = j >> 9;
        int p = j & (P_DIM - 1);
        float cre = C[(size_t)j * 2];
        float cim = C[(size_t)j * 2 + 1];
        W2[(size_t)h * N2 + p]         = (unsigned short)f2bf_bits( 2.0f * cre);
        W2[(size_t)h * N2 + P_DIM + p] = (unsigned short)f2bf_bits(-2.0f * cim);
    }
}

__global__ void convert_sig(const float* __restrict__ in,
                            unsigned short* __restrict__ out) {
    size_t i = ((size_t)blockIdx.x * 256 + threadIdx.x) * 4;
    float4 v = *(const float4*)(in + i);
    ushort4 o;
    o.x = (unsigned short)f2bf_bits(v.x);
    o.y = (unsigned short)f2bf_bits(v.y);
    o.z = (unsigned short)f2bf_bits(v.z);
    o.w = (unsigned short)f2bf_bits(v.w);
    *(ushort4*)(out + i) = o;
}

// ---------------------------------------------------------------------------
// bf16 MFMA GEMM, 256x256 tile, 8-phase deep-pipelined schedule (T2+T3+T4+T5).
// Out[m][n] = sum_k A[m][k]*W[n][k].  A: M x K bf16, W: N x K bf16, K=1024.
//
// 512 thr = 8 waves in 2(m) x 4(n); per-wave output 128x64 = acc[8][4] frags
// of 16x16x32 MFMA. LDS 128 KiB = 2 dbuf x (A 256x64 | W 256x64) bf16.
// Grid 256 = 64 m-blocks x 4 n-blocks -> exactly 1 WG/CU (no tail).
//
// Per K-tile (BK=64): 4 phases, each {ds_read subtile || issue
// global_load_lds -> s_barrier -> lgkmcnt(0) -> setprio(1) -> 16 MFMA ->
// setprio(0) -> s_barrier}.  Quadrants: P0 reads A[mi0-3]+W[ni0-1] (12 rd),
// P1 reads W[ni2-3] (4 rd), P2 reads A[mi4-7] (8 rd), P3 no reads; W-frags
// are held in registers across phases (halves LDS B-traffic).
//
// Counted vmcnt (T4): staging runs ahead -- while computing kt we issue
// A1/W1(kt+1) at P0 (other buffer, fully drained last block), W0(kt+2) at P2
// (own buffer B-half0: its last reads drain at P1's barrier), A0(kt+2) at P3
// (A-half0 drains at P2's barrier). Checkpoint once per K-tile:
// s_waitcnt vmcnt(4) + s_barrier -> kt+1 fully resident, only the P2/P3
// prefetches (4 loads) still in flight. Never vmcnt(0) in steady state.
//
// LDS k-slot swizzle (carried over, read-side bank-uniform): LDS[row][slot]
// holds global quad (slot - (row>>1))&7, applied by rotating the *global*
// source quad per lane at stage time (keeps global_load_lds dest linear);
// reads use sl = (kk*4 + fq + (fr>>1)) & 7.
//
// XCD swizzle: XCD x owns m-blocks [8x, 8x+8), 4 n-blocks consecutive ->
// A-panel L2 reuse x4 within an XCD.
// MODE 0: bf16 out via LDS-transposed coalesced 16B stores (pad 264).
// MODE 1: f32 out, + D[col]*bf2f(SigBf[row][col]) fused.
// ---------------------------------------------------------------------------
template <int MODE>
__global__ __launch_bounds__(512, 2) void gemm_mfma(
    const unsigned short* __restrict__ A,
    const unsigned short* __restrict__ W,
    void* __restrict__ Out, int K,
    const float* __restrict__ Dvec, const unsigned short* __restrict__ SigBf)
{
    __shared__ unsigned short smem[65536];   // 128 KiB

    const int tid  = threadIdx.x;
    const int lane = tid & 63;
    const int wid  = tid >> 6;      // 0..7
    const int wm   = wid >> 2;      // 0..1
    const int wn   = wid & 3;       // 0..3

    // XCD swizzle: 256 WGs; xcd = id&7 owns 32 consecutive wg slots
    const int id  = blockIdx.x;
    const int wg  = (id & 7) * 32 + (id >> 3);   // 0..255
    const int m0  = (wg >> 2) * 256;             // 64 m-blocks
    const int n0  = (wg & 3) * 256;              // 4  n-blocks

    const int fr  = lane & 15;       // m-row / n-col within 16
    const int fq  = lane >> 4;       // k-quad within 32
    const int ks0 = ((fq + (fr >> 1)) & 7) * 8;  // swizzled slot (kk=0), ushorts
    const int ks1 = ks0 ^ 32;                    // kk=1 (+4 slots mod 8)
    const int qg  = ((tid & 7) - ((tid >> 4) & 7)) & 7;   // stage source quad

    const int NKT = K >> 6;          // 16 K-tiles

    // stage one 128-row half-tile (16 KB) = 2 global_load_lds per wave slice
    auto STAGE = [&](const unsigned short* __restrict__ Mat, int mn0,
                     int half, int kt, int bofs) {
        const unsigned short* s = Mat
            + (size_t)(mn0 + half * 128 + (tid >> 3)) * K + (kt << 6) + qg * 8;
        unsigned short* d = smem + (kt & 1) * 32768 + bofs
            + (half * 1024 + wid * 64) * 8;
        ASYNC_COPY16(s, d);
        ASYNC_COPY16(s + (size_t)64 * K, d + 4096);
    };

    f32x4 acc[8][4] = {};

    // ---- prologue: kt0 complete (8 loads) + kt1 A-half0, W-half0 (4 loads)
    STAGE(A, m0, 0, 0, 0);      STAGE(A, m0, 1, 0, 0);
    STAGE(W, n0, 0, 0, 16384);  STAGE(W, n0, 1, 0, 16384);
    STAGE(W, n0, 0, 1, 16384);  STAGE(A, m0, 0, 1, 0);
    asm volatile("s_waitcnt vmcnt(4)" ::: "memory");   // kt0's 8 loads landed
    __builtin_amdgcn_s_barrier();

    #pragma unroll 1
    for (int kt = 0; kt < NKT; ++kt) {
        const unsigned short* Ab =
            smem + (kt & 1) * 32768 + (wm * 128 + fr) * 64;
        const unsigned short* Wb =
            smem + (kt & 1) * 32768 + 16384 + (wn * 64 + fr) * 64;
        bf16x8 af[4][2], w0[2][2], w1[2][2];

        // ================= phase 0 : Q0 = acc[0..3][0..1] =================
        #pragma unroll
        for (int mi = 0; mi < 4; ++mi) {
            af[mi][0] = *(const bf16x8*)&Ab[mi * 1024 + ks0];
            af[mi][1] = *(const bf16x8*)&Ab[mi * 1024 + ks1];
        }
        #pragma unroll
        for (int ni = 0; ni < 2; ++ni) {
            w0[ni][0] = *(const bf16x8*)&Wb[ni * 1024 + ks0];
            w0[ni][1] = *(const bf16x8*)&Wb[ni * 1024 + ks1];
        }
        if (kt + 1 < NKT) {                 // other buffer: fully drained
            STAGE(A, m0, 1, kt + 1, 0);
            STAGE(W, n0, 1, kt + 1, 16384);
        }
        __builtin_amdgcn_s_barrier();
        asm volatile("s_waitcnt lgkmcnt(0)" ::: "memory");
        __builtin_amdgcn_sched_barrier(0);
        __builtin_amdgcn_s_setprio(1);
        #pragma unroll
        for (int mi = 0; mi < 4; ++mi)
            #pragma unroll
            for (int ni = 0; ni < 2; ++ni) {
                acc[mi][ni] = __builtin_amdgcn_mfma_f32_16x16x32_bf16(
                    af[mi][0], w0[ni][0], acc[mi][ni], 0, 0, 0);
                acc[mi][ni] = __builtin_amdgcn_mfma_f32_16x16x32_bf16(
                    af[mi][1], w0[ni][1], acc[mi][ni], 0, 0, 0);
            }
        __builtin_amdgcn_s_setprio(0);
        __builtin_amdgcn_s_barrier();

        // ================= phase 1 : Q1 = acc[0..3][2..3] =================
        #pragma unroll
        for (int ni = 0; ni < 2; ++ni) {
            w1[ni][0] = *(const bf16x8*)&Wb[(2 + ni) * 1024 + ks0];
            w1[ni][1] = *(const bf16x8*)&Wb[(2 + ni) * 1024 + ks1];
        }
        __builtin_amdgcn_s_barrier();
        asm volatile("s_waitcnt lgkmcnt(0)" ::: "memory");
        __builtin_amdgcn_sched_barrier(0);
        __builtin_amdgcn_s_setprio(1);
        #pragma unroll
        for (int mi = 0; mi < 4; ++mi)
            #pragma unroll
            for (int ni = 0; ni < 2; ++ni) {
                acc[mi][2 + ni] = __builtin_amdgcn_mfma_f32_16x16x32_bf16(
                    af[mi][0], w1[ni][0], acc[mi][2 + ni], 0, 0, 0);
                acc[mi][2 + ni] = __builtin_amdgcn_mfma_f32_16x16x32_bf16(
                    af[mi][1], w1[ni][1], acc[mi][2 + ni], 0, 0, 0);
            }
        __builtin_amdgcn_s_setprio(0);
        __builtin_amdgcn_s_barrier();

        // ================= phase 2 : Q2 = acc[4..7][0..1] =================
        #pragma unroll
        for (int mi = 0; mi < 4; ++mi) {
            af[mi][0] = *(const bf16x8*)&Ab[4096 + mi * 1024 + ks0];
            af[mi][1] = *(const bf16x8*)&Ab[4096 + mi * 1024 + ks1];
        }
        if (kt + 2 < NKT)                   // own buffer B-half0: drained @P1
            STAGE(W, n0, 0, kt + 2, 16384);
        __builtin_amdgcn_s_barrier();
        asm volatile("s_waitcnt lgkmcnt(0)" ::: "memory");
        __builtin_amdgcn_sched_barrier(0);
        __builtin_amdgcn_s_setprio(1);
        #pragma unroll
        for (int mi = 0; mi < 4; ++mi)
            #pragma unroll
            for (int ni = 0; ni < 2; ++ni) {
                acc[4 + mi][ni] = __builtin_amdgcn_mfma_f32_16x16x32_bf16(
                    af[mi][0], w0[ni][0], acc[4 + mi][ni], 0, 0, 0);
                acc[4 + mi][ni] = __builtin_amdgcn_mfma_f32_16x16x32_bf16(
                    af[mi][1], w0[ni][1], acc[4 + mi][ni], 0, 0, 0);
            }
        __builtin_amdgcn_s_setprio(0);
        __builtin_amdgcn_s_barrier();

        // ================= phase 3 : Q3 = acc[4..7][2..3] =================
        if (kt + 2 < NKT)                   // own buffer A-half0: drained @P2
            STAGE(A, m0, 0, kt + 2, 0);
        __builtin_amdgcn_s_barrier();
        __builtin_amdgcn_s_setprio(1);
        #pragma unroll
        for (int mi = 0; mi < 4; ++mi)
            #pragma unroll
            for (int ni = 0; ni < 2; ++ni) {
                acc[4 + mi][2 + ni] = __builtin_amdgcn_mfma_f32_16x16x32_bf16(
                    af[mi][0], w1[ni][0], acc[4 + mi][2 + ni], 0, 0, 0);
                acc[4 + mi][2 + ni] = __builtin_amdgcn_mfma_f32_16x16x32_bf16(
                    af[mi][1], w1[ni][1], acc[4 + mi][2 + ni], 0, 0, 0);
            }
        __builtin_amdgcn_s_setprio(0);
        // ---- checkpoint: kt+1 must be fully resident; only the P2/P3
        // prefetches (4 loads) may remain in flight. Final tiles drain fully.
        if (kt == NKT - 2)
            asm volatile("s_waitcnt vmcnt(0)" ::: "memory");
        else
            asm volatile("s_waitcnt vmcnt(4)" ::: "memory");
        __builtin_amdgcn_s_barrier();
    }

    // C/D layout (m89): col = lane&15, row = (lane>>4)*4 + reg
    if (MODE == 0) {
        // bf16 out: transpose through LDS, two 128x256 halves (pad 264)
        unsigned short* T = smem;
        #pragma unroll
        for (int h = 0; h < 2; ++h) {
            __syncthreads();
            if (wm == h) {
                #pragma unroll
                for (int mi = 0; mi < 8; ++mi)
                    #pragma unroll
                    for (int ni = 0; ni < 4; ++ni)
                        #pragma unroll
                        for (int r = 0; r < 4; ++r) {
                            int lrow = mi * 16 + fq * 4 + r;      // 0..127
                            int lcol = wn * 64 + ni * 16 + fr;    // 0..255
                            T[lrow * 264 + lcol] =
                                (unsigned short)f2bf_bits(acc[mi][ni][r]);
                        }
            }
            __syncthreads();
            // 128 rows x 256 cols = 4096 chunks of 16 B; 512 thr -> 8 iters
            #pragma unroll
            for (int jj = 0; jj < 8; ++jj) {
                int chunk = jj * 512 + tid;
                int row = chunk >> 5;              // 0..127
                int co  = (chunk & 31) * 8;        // 0..248
                *(ulonglong2*)((unsigned short*)Out +
                    (size_t)(m0 + h * 128 + row) * 1024 + n0 + co) =
                    *(const ulonglong2*)&T[row * 264 + co];
            }
        }
    } else {
        float Dl[4];
        #pragma unroll
        for (int ni = 0; ni < 4; ++ni)
            Dl[ni] = Dvec[n0 + wn * 64 + ni * 16 + fr];
        #pragma unroll
        for (int mi = 0; mi < 8; ++mi) {
            #pragma unroll
            for (int ni = 0; ni < 4; ++ni) {
                #pragma unroll
                for (int r = 0; r < 4; ++r) {
                    int row = m0 + wm * 128 + mi * 16 + fq * 4 + r;
                    int col = n0 + wn * 64 + ni * 16 + fr;
                    float v = acc[mi][ni][r];
                    v = fmaf(Dl[ni], bf2f(SigBf[(size_t)row * 1024 + col]), v);
                    ((float*)Out)[(size_t)row * 1024 + col] = v;
                }
            }
        }
    }
}

// ---------------------------------------------------------------------------
// Scan pass A: per (b, chunk) local scan (zero init) -> chunk-end sums.
// ---------------------------------------------------------------------------
__global__ __launch_bounds__(256) void scan_sums(
    const unsigned short* __restrict__ Bu, const float* __restrict__ lam,
    float* __restrict__ S)
{
    int b = blockIdx.x, c = blockIdx.y, t = threadIdx.x;
    int p0 = 2 * t, p1 = 2 * t + 1;
    float lr0 = lam[p0], li0 = lam[P_DIM + p0];
    float lr1 = lam[p1], li1 = lam[P_DIM + p1];
    const unsigned* base =
        (const unsigned*)(Bu + ((size_t)b * L_SEQ + (size_t)c * T_CHUNK) * N2);
    float xr0 = 0, xi0 = 0, xr1 = 0, xi1 = 0;
    for (int j0 = 0; j0 < T_CHUNK; j0 += 8) {
        unsigned R[8], I[8];
        #pragma unroll
        for (int j = 0; j < 8; ++j) {
            R[j] = base[(size_t)(j0 + j) * 512 + t];
            I[j] = base[(size_t)(j0 + j) * 512 + 256 + t];
        }
        #pragma unroll
        for (int j = 0; j < 8; ++j) {
            float nr0 = fmaf(lr0, xr0, fmaf(-li0, xi0, bf_lo(R[j])));
            float ni0 = fmaf(lr0, xi0, fmaf( li0, xr0, bf_lo(I[j])));
            float nr1 = fmaf(lr1, xr1, fmaf(-li1, xi1, bf_hi(R[j])));
            float ni1 = fmaf(lr1, xi1, fmaf( li1, xr1, bf_hi(I[j])));
            xr0 = nr0; xi0 = ni0; xr1 = nr1; xi1 = ni1;
        }
    }
    float* Sb = S + ((size_t)(b * NC + c) * 2) * P_DIM;
    Sb[p0] = xr0; Sb[p1] = xr1;
    Sb[P_DIM + p0] = xi0; Sb[P_DIM + p1] = xi1;
}

// Pass B: carries. cin[b][0]=0; cin[c] = lam^T_CHUNK * cin[c-1] + S[c-1].
__global__ __launch_bounds__(512) void scan_carry(
    const float* __restrict__ S, const float* __restrict__ lam,
    float* __restrict__ CIN)
{
    int b = blockIdx.x, p = threadIdx.x;
    float lr = lam[p], li = lam[P_DIM + p];
    float pr = lr, pi = li;                 // lam^64 via 6 squarings
    #pragma unroll
    for (int i = 0; i < 6; ++i) {
        float nr = pr * pr - pi * pi;
        float ni = 2.0f * pr * pi;
        pr = nr; pi = ni;
    }
    float cr = 0, ci = 0;
    for (int c = 0; c < NC; ++c) {
        float* Cb = CIN + ((size_t)(b * NC + c) * 2) * P_DIM;
        Cb[p] = cr; Cb[P_DIM + p] = ci;
        const float* Sb = S + ((size_t)(b * NC + c) * 2) * P_DIM;
        float sr = Sb[p], si = Sb[P_DIM + p];
        float nr = fmaf(pr, cr, fmaf(-pi, ci, sr));
        float ni = fmaf(pr, ci, fmaf( pi, cr, si));
        cr = nr; ci = ni;
    }
}

// Pass C: x = cin; x = lam*x + u; overwrite Bu with xs (bf16); emit state.
__global__ __launch_bounds__(256) void scan_apply(
    unsigned short* __restrict__ Bu, const float* __restrict__ lam,
    const float* __restrict__ CIN, float* __restrict__ out_state,
    int interleaved)
{
    int b = blockIdx.x, c = blockIdx.y, t = threadIdx.x;
    int p0 = 2 * t, p1 = 2 * t + 1;
    float lr0 = lam[p0], li0 = lam[P_DIM + p0];
    float lr1 = lam[p1], li1 = lam[P_DIM + p1];
    const float* Cb = CIN + ((size_t)(b * NC + c) * 2) * P_DIM;
    float xr0 = Cb[p0], xi0 = Cb[P_DIM + p0];
    float xr1 = Cb[p1], xi1 = Cb[P_DIM + p1];
    unsigned* base =
        (unsigned*)(Bu + ((size_t)b * L_SEQ + (size_t)c * T_CHUNK) * N2);
    for (int j0 = 0; j0 < T_CHUNK; j0 += 8) {
        unsigned R[8], I[8];
        #pragma unroll
        for (int j = 0; j < 8; ++j) {
            R[j] = base[(size_t)(j0 + j) * 512 + t];
            I[j] = base[(size_t)(j0 + j) * 512 + 256 + t];
        }
        #pragma unroll
        for (int j = 0; j < 8; ++j) {
            float nr0 = fmaf(lr0, xr0, fmaf(-li0, xi0, bf_lo(R[j])));
            float ni0 = fmaf(lr0, xi0, fmaf( li0, xr0, bf_lo(I[j])));
            float nr1 = fmaf(lr1, xr1, fmaf(-li1, xi1, bf_hi(R[j])));
            float ni1 = fmaf(lr1, xi1, fmaf( li1, xr1, bf_hi(I[j])));
            xr0 = nr0; xi0 = ni0; xr1 = nr1; xi1 = ni1;
            R[j] = f2bf_bits(nr0) | (f2bf_bits(nr1) << 16);
            I[j] = f2bf_bits(ni0) | (f2bf_bits(ni1) << 16);
        }
        #pragma unroll
        for (int j = 0; j < 8; ++j) {
            base[(size_t)(j0 + j) * 512 + t]       = R[j];
            base[(size_t)(j0 + j) * 512 + 256 + t] = I[j];
        }
    }
    if (c == NC - 1) {
        if (interleaved) {
            out_state[((size_t)b * P_DIM + p0) * 2]     = xr0;
            out_state[((size_t)b * P_DIM + p0) * 2 + 1] = xi0;
            out_state[((size_t)b * P_DIM + p1) * 2]     = xr1;
            out_state[((size_t)b * P_DIM + p1) * 2 + 1] = xi1;
        } else {
            out_state[(size_t)b * P_DIM + p0] = xr0;
            out_state[(size_t)b * P_DIM + p1] = xr1;
        }
    }
}

// ---------------------------------------------------------------------------
extern "C" void kernel_launch(void* const* d_in, const int* in_sizes, int n_in,
                              void* d_out, int out_size, void* d_ws, size_t ws_size,
                              hipStream_t stream)
{
    const float* signal   = (const float*)d_in[0];
    // d_in[1] = prev_state: never reaches the scan's b-component -> no effect
    const float* Lre      = (const float*)d_in[2];
    const float* Lim      = (const float*)d_in[3];
    const float* B        = (const float*)d_in[4];
    const float* C        = (const float*)d_in[5];
    const float* Dv       = (const float*)d_in[6];
    const float* log_step = (const float*)d_in[7];

    // ws layout (bytes)
    char* ws = (char*)d_ws;
    unsigned short* sigbf = (unsigned short*)ws;                      // 32 MB
    unsigned short* Bubf  = (unsigned short*)(ws + 33554432);         // 32 MB
    unsigned short* W1bf  = (unsigned short*)(ws + 67108864);         // 2 MB
    unsigned short* W2bf  = (unsigned short*)(ws + 69206016);         // 2 MB
    float*          lam   = (float*)(ws + 71303168);                  // 8 KB
    float*          S     = (float*)(ws + 71311360);                  // 512 KB
    float*          CIN   = (float*)(ws + 71835648);                  // 512 KB
    size_t need = 72359936;
    if (ws_size < need) return;

    float* y_out = (float*)d_out;
    float* state_out = y_out + (size_t)M_DIM * H_DIM;
    int interleaved = (out_size - M_DIM * H_DIM) >= 2 * BATCH_N * P_DIM;

    setup_lam<<<dim3(2), dim3(256), 0, stream>>>(Lre, Lim, log_step, lam);
    build_W<<<dim3((2 * P_DIM * H_DIM) / 256), dim3(256), 0, stream>>>(
        B, C, lam, W1bf, W2bf);
    convert_sig<<<dim3((M_DIM * H_DIM) / 1024), dim3(256), 0, stream>>>(signal, sigbf);

    // GEMM1: Bu[m][n] = sum_h sig[m][h] * W1[n][h]   (bf16 out)
    gemm_mfma<0><<<dim3(256), dim3(512), 0, stream>>>(
        sigbf, W1bf, Bubf, H_DIM, nullptr, nullptr);

    scan_sums<<<dim3(BATCH_N, NC), dim3(256), 0, stream>>>(Bubf, lam, S);
    scan_carry<<<dim3(BATCH_N), dim3(512), 0, stream>>>(S, lam, CIN);
    scan_apply<<<dim3(BATCH_N, NC), dim3(256), 0, stream>>>(
        Bubf, lam, CIN, state_out, interleaved);

    // GEMM2: y[m][h] = sum_k xs[m][k]*W2[h][k] + D[h]*sig[m][h]  (fp32 out)
    gemm_mfma<1><<<dim3(256), dim3(512), 0, stream>>>(
        Bubf, W2bf, y_out, N2, Dv, sigbf);
}